// Round 8
// baseline (273.097 us; speedup 1.0000x reference)
//
#include <hip/hip_runtime.h>
#include <stdint.h>

typedef unsigned short u16;
typedef unsigned int u32;
typedef __attribute__((ext_vector_type(8))) short bf16x8;   // 8 bf16 = 4 VGPRs (MFMA A/B frag)
typedef __attribute__((ext_vector_type(8))) unsigned short u16x8;
typedef __attribute__((ext_vector_type(4))) float f32x4;
typedef __attribute__((ext_vector_type(4))) int i32x4;
typedef __attribute__((ext_vector_type(4))) unsigned int u32x4;

__device__ __forceinline__ u16 f2bf(float f) {
  uint32_t u = __builtin_bit_cast(uint32_t, f);
  u += 0x7fffu + ((u >> 16) & 1u);   // RNE
  return (u16)(u >> 16);
}

// async global->LDS, 16B per lane; LDS dest must be wave-uniform base (+lane*16 implicit)
#define GLD16(g, l)                                                         \
  __builtin_amdgcn_global_load_lds(                                         \
      (const __attribute__((address_space(1))) void*)(g),                   \
      (__attribute__((address_space(3))) void*)(l), 16, 0, 0)

// ---------------- elementwise prep kernels (r3-verified) ----------------

__global__ __launch_bounds__(256) void cvt_f32_bf16(const float* __restrict__ src,
                                                    u16* __restrict__ dst, int n8) {
  int t = blockIdx.x * 256 + threadIdx.x;
  if (t >= n8) return;
  f32x4 a = ((const f32x4*)src)[2 * t];
  f32x4 b = ((const f32x4*)src)[2 * t + 1];
  u16x8 o;
  o[0] = f2bf(a[0]); o[1] = f2bf(a[1]); o[2] = f2bf(a[2]); o[3] = f2bf(a[3]);
  o[4] = f2bf(b[0]); o[5] = f2bf(b[1]); o[6] = f2bf(b[2]); o[7] = f2bf(b[3]);
  ((u16x8*)dst)[t] = o;
}

__global__ __launch_bounds__(256) void bias_init(float* __restrict__ out,
                                                 const float* __restrict__ b,
                                                 int N, int n4) {
  int t = blockIdx.x * 256 + threadIdx.x;
  if (t >= n4) return;
  int idx = t * 4;
  int n = idx & (N - 1);          // N is a power of two (2048)
  *(f32x4*)(out + idx) = *(const f32x4*)(b + n);
}

// ---- NT GEMM with fused INT4 dequant of B: C[M,N] = A[M,K] * dq(Q)[N,K]^T ----
// BM=128, BN=32*NJ. 4 waves 2x2, wave = 64 x 16*NJ via 4xNJ MFMA 16x16x32, BK=32.
// A (bf16, 64B rows): r1-verified GLD16 staging + swizzle (0 conflicts measured).
// B (int32 q, 128B rows): r3-verified 128B-row GLD16 staging — 8 rows x 8 slots
//   of 16B per load, pre-swizzled global slot ^(row&7), swizzled read (0 conflicts
//   measured r3). Frag = 2x ds_read_b128 of int32 -> cvt to bf16 in regs, placed
//   AFTER the overwrite-barrier (register-only, overlaps STAGE issue).
// scale/zero per (row, 128-group): preloaded once per block into padded LDS
//   (stride 2*GC+2 floats -> conflict-free b64 reads; broadcast across quads).
// Sync = r6/r7-verified 2-deep counted vmcnt; VM = 2+NJ GLD16s/stage/wave.
template <int NJ, int GC, bool RELU, bool OUT_BF16, bool ATOMIC>
__global__ __launch_bounds__(256) void gemm_dqf(const u16* __restrict__ A,
                                                const int* __restrict__ Q,
                                                const float* __restrict__ S,
                                                const float* __restrict__ Z,
                                                const float* __restrict__ bias,
                                                void* __restrict__ Cout,
                                                int N, int K, int kChunk) {
  constexpr int ROWS = 32 * NJ;          // BN
  constexpr int SZST = 2 * GC + 2;       // padded float stride per row
  constexpr int VM = 2 + NJ;             // GLD16s per stage per wave
  __shared__ u16 As[2][128 * 32];        // 2 x 8 KB
  __shared__ int Bq[2][ROWS * 32];       // 2 x 4KB*NJ
  __shared__ float szL[ROWS * SZST];     // ~8.7-9.2 KB
  const int tid = threadIdx.x;
  const int wave = tid >> 6;
  const int lane = tid & 63;
  const int m0 = blockIdx.y << 7;
  const int n0 = blockIdx.x * ROWS;
  const int kStart = blockIdx.z * kChunk;
  const int srow = lane >> 2;                                  // A: 16 rows x 4x16B
  const int scolA = (((lane & 3) ^ ((lane >> 3) & 3)) << 3);   // A pre-swizzled chunk
  const int schB = (((lane & 7) ^ ((lane >> 3) & 7)) << 2);    // B pre-swizzled slot (ints)
  const int wm = (wave >> 1) << 6;
  const int wn = (wave & 1) * (16 * NJ);
  const int quad = lane >> 4;
  const int l15 = lane & 15;
  const int csA = ((quad ^ ((l15 >> 1) & 3)) << 3);            // A swizzled read offset

  const u16* Ab = A + (size_t)(m0 + 32 * wave + srow) * K + kStart + scolA;
  const int* Qb = Q + (size_t)(n0 + 8 * NJ * wave + (lane >> 3)) * K + kStart + schB;
  const int ldsA = (32 * wave) * 32;     // u16 offset, wave's 32 A-rows
  const int ldsB = (8 * NJ * wave) * 32; // int offset, wave's 8*NJ B-rows
  const size_t rsA = (size_t)16 * K;
  const size_t rsB = (size_t)8 * K;
  const int nT = kChunk >> 5;            // 64 (gemm1) / 32 (gemm2)
  const int nG = K >> 7;
  const int g0 = kStart >> 7;

  // preload (scale, zero) for this tile's ROWS x GC groups (ROWS*GC = 1024 both cfgs)
  for (int p = tid; p < ROWS * GC; p += 256) {
    const int r = p / GC;                // GC is a compile-time power of 2
    const int gr = p - r * GC;
    const size_t si = (size_t)(n0 + r) * nG + g0 + gr;
    szL[r * SZST + 2 * gr] = S[si];
    szL[r * SZST + 2 * gr + 1] = Z[si];
  }
  __syncthreads();   // sz visible to all waves; drains vmcnt -> clean counting

  f32x4 acc[4][NJ];
#pragma unroll
  for (int i = 0; i < 4; i++)
#pragma unroll
    for (int j = 0; j < NJ; j++) acc[i][j] = (f32x4){0.f, 0.f, 0.f, 0.f};

  // stage K-step t_ into buffer bi_ : exactly VM GLD16 per wave
#define STAGE(bi_, t_)                                          \
  do {                                                          \
    const int ko_ = (t_) << 5;                                  \
    GLD16(Ab + ko_, &As[bi_][ldsA]);                            \
    GLD16(Ab + ko_ + rsA, &As[bi_][ldsA + 512]);                \
    GLD16(Qb + ko_, &Bq[bi_][ldsB]);                            \
    GLD16(Qb + ko_ + rsB, &Bq[bi_][ldsB + 256]);                \
    if (NJ == 4) {                                              \
      GLD16(Qb + ko_ + 2 * rsB, &Bq[bi_][ldsB + 512]);          \
      GLD16(Qb + ko_ + 3 * rsB, &Bq[bi_][ldsB + 768]);          \
    }                                                           \
  } while (0)

  bf16x8 af[4], bf[NJ];
  i32x4 blo[NJ], bhi[NJ];
  float2 bsz[NJ];
  // all LDS reads into regs (no VALU): A frags + raw B ints + scale/zero
#define LOADRAW(bi_, gRel_)                                                   \
  do {                                                                        \
    _Pragma("unroll") for (int i = 0; i < 4; i++)                             \
        af[i] = *(const bf16x8*)&As[bi_][(wm + i * 16 + l15) * 32 + csA];     \
    _Pragma("unroll") for (int j = 0; j < NJ; j++) {                          \
      const int r_ = wn + j * 16 + l15;                                       \
      const int s0_ = (((2 * quad) ^ (r_ & 7)) << 2);                         \
      blo[j] = *(const i32x4*)&Bq[bi_][r_ * 32 + s0_];                        \
      bhi[j] = *(const i32x4*)&Bq[bi_][r_ * 32 + (s0_ ^ 4)];                  \
      bsz[j] = *(const float2*)&szL[r_ * SZST + 2 * (gRel_)];                 \
    }                                                                         \
  } while (0)

  // register-only dequant: ((float)q - zp) * sc, RNE bf16 via v_cvt_pk_bf16_f32
#define CVTB()                                                                 \
  do {                                                                         \
    _Pragma("unroll") for (int j = 0; j < NJ; j++) {                           \
      const float sc_ = bsz[j].x, zp_ = bsz[j].y;                              \
      u32x4 w_;                                                                \
      _Pragma("unroll") for (int c = 0; c < 2; c++) {                          \
        float e0 = ((float)blo[j][2 * c] - zp_) * sc_;                         \
        float e1 = ((float)blo[j][2 * c + 1] - zp_) * sc_;                     \
        asm("v_cvt_pk_bf16_f32 %0, %1, %2" : "=v"(w_[c]) : "v"(e0), "v"(e1));  \
        float e2 = ((float)bhi[j][2 * c] - zp_) * sc_;                         \
        float e3 = ((float)bhi[j][2 * c + 1] - zp_) * sc_;                     \
        asm("v_cvt_pk_bf16_f32 %0, %1, %2" : "=v"(w_[2 + c]) : "v"(e2), "v"(e3)); \
      }                                                                        \
      bf[j] = __builtin_bit_cast(bf16x8, w_);                                  \
    }                                                                          \
  } while (0)

#define DOMFMA()                                                              \
  do {                                                                        \
    _Pragma("unroll") for (int i = 0; i < 4; i++)                             \
        _Pragma("unroll") for (int j = 0; j < NJ; j++)                        \
            acc[i][j] = __builtin_amdgcn_mfma_f32_16x16x32_bf16(              \
                af[i], bf[j], acc[i][j], 0, 0, 0);                            \
  } while (0)

  // prologue: fill the 2-deep pipe (2*VM loads in flight per wave)
  STAGE(0, 0);
  STAGE(1, 1);

  for (int t = 0; t < nT - 2; ++t) {
    // outstanding = stages {t, t+1} = 2*VM; retire the oldest VM (stage t)
    asm volatile("s_waitcnt vmcnt(%0)" ::"i"(VM) : "memory");
    __builtin_amdgcn_s_barrier();              // stage(t) visible in LDS
    LOADRAW(t & 1, t >> 2);
    asm volatile("s_waitcnt lgkmcnt(0)" ::: "memory");   // all LDS reads in regs
    __builtin_amdgcn_sched_barrier(0);         // rule #18
    __builtin_amdgcn_s_barrier();              // all waves done reading buf
    STAGE(t & 1, t + 2);                       // overwrite with tile t+2
    CVTB();                                    // register-only, overlaps staging
    DOMFMA();
  }
  // t = nT-2
  asm volatile("s_waitcnt vmcnt(%0)" ::"i"(VM) : "memory");
  __builtin_amdgcn_s_barrier();
  LOADRAW((nT - 2) & 1, (nT - 2) >> 2);
  asm volatile("s_waitcnt lgkmcnt(0)" ::: "memory");
  __builtin_amdgcn_sched_barrier(0);
  CVTB();
  DOMFMA();
  // t = nT-1: drain
  asm volatile("s_waitcnt vmcnt(0)" ::: "memory");
  __builtin_amdgcn_s_barrier();
  LOADRAW((nT - 1) & 1, (nT - 1) >> 2);
  asm volatile("s_waitcnt lgkmcnt(0)" ::: "memory");
  __builtin_amdgcn_sched_barrier(0);
  CVTB();
  DOMFMA();

#undef STAGE
#undef LOADRAW
#undef CVTB
#undef DOMFMA

  // epilogue: C/D layout col=lane&15, row=quad*4+reg (verified m89/m91)
#pragma unroll
  for (int i = 0; i < 4; i++) {
#pragma unroll
    for (int j = 0; j < NJ; j++) {
      const int col = n0 + wn + j * 16 + l15;
      float bv = 0.f;
      if (!ATOMIC) bv = bias[col];
#pragma unroll
      for (int r = 0; r < 4; r++) {
        const int row = m0 + wm + i * 16 + quad * 4 + r;
        float v = acc[i][j][r];
        if (ATOMIC) {
          atomicAdd((float*)Cout + (size_t)row * N + col, v);
        } else {
          v += bv;
          if (RELU) v = v > 0.f ? v : 0.f;
          if (OUT_BF16)
            ((u16*)Cout)[(size_t)row * N + col] = f2bf(v);
          else
            ((float*)Cout)[(size_t)row * N + col] = v;
        }
      }
    }
  }
}

// ---------------- launch ----------------

extern "C" void kernel_launch(void* const* d_in, const int* in_sizes, int n_in,
                              void* d_out, int out_size, void* d_ws, size_t ws_size,
                              hipStream_t stream) {
  const float* x  = (const float*)d_in[0];
  const int*   q1 = (const int*)d_in[1];
  const float* s1 = (const float*)d_in[2];
  const float* z1 = (const float*)d_in[3];
  const float* b1 = (const float*)d_in[4];
  const int*   q2 = (const int*)d_in[5];
  const float* s2 = (const float*)d_in[6];
  const float* z2 = (const float*)d_in[7];
  const float* b2 = (const float*)d_in[8];
  float* out = (float*)d_out;

  const int B = 512, D_IN = 2048, D_H = 8192, D_OUT = 2048;

  char* ws = (char*)d_ws;
  u16* xb = (u16*)(ws);                                  // 2 MB: x bf16 [512][2048]
  u16* hb = (u16*)(ws + (size_t)2 * 1024 * 1024);        // 8 MB: h bf16 [512][8192]

  // 1. x -> bf16
  cvt_f32_bf16<<<(B * D_IN / 8 + 255) / 256, 256, 0, stream>>>(x, xb, B * D_IN / 8);
  // 2. h = relu(x @ dq(q1)^T + b1), bf16 out, dequant fused into B staging.
  //    BN=64 -> grid (128,4) = 512 blocks. K=2048 -> GC=16, nT=64.
  {
    dim3 g1(D_H / 64, B / 128, 1);
    gemm_dqf<2, 16, true, true, false><<<g1, 256, 0, stream>>>(
        xb, q1, s1, z1, b1, hb, D_H, D_IN, D_IN);
  }
  // 3. out = b2 broadcast, then split-K=8 atomic: out += h @ dq(q2)^T.
  //    128x128 -> grid (16,4,8) = 512 blocks. kChunk=1024 -> GC=8, nT=32.
  bias_init<<<(B * D_OUT / 4 + 255) / 256, 256, 0, stream>>>(out, b2, D_OUT, B * D_OUT / 4);
  {
    dim3 g2(D_OUT / 128, B / 128, 8);
    gemm_dqf<4, 8, false, false, true><<<g2, 256, 0, stream>>>(
        hb, q2, s2, z2, nullptr, out, D_OUT, D_H, D_H / 8);
  }
}

// Round 9
// 249.282 us; speedup vs baseline: 1.0955x; 1.0955x over previous
//
#include <hip/hip_runtime.h>
#include <stdint.h>

typedef unsigned short u16;
typedef __attribute__((ext_vector_type(8))) short bf16x8;   // 8 bf16 = 4 VGPRs (MFMA A/B frag)
typedef __attribute__((ext_vector_type(8))) unsigned short u16x8;
typedef __attribute__((ext_vector_type(4))) float f32x4;
typedef __attribute__((ext_vector_type(4))) int i32x4;

__device__ __forceinline__ u16 f2bf(float f) {
  uint32_t u = __builtin_bit_cast(uint32_t, f);
  u += 0x7fffu + ((u >> 16) & 1u);   // RNE
  return (u16)(u >> 16);
}

// async global->LDS, 16B per lane; LDS dest must be wave-uniform base (+lane*16 implicit)
#define GLD16(g, l)                                                         \
  __builtin_amdgcn_global_load_lds(                                         \
      (const __attribute__((address_space(1))) void*)(g),                   \
      (__attribute__((address_space(3))) void*)(l), 16, 0, 0)

// ---------------- elementwise prep kernels (r3-verified) ----------------

__global__ __launch_bounds__(256) void cvt_f32_bf16(const float* __restrict__ src,
                                                    u16* __restrict__ dst, int n8) {
  int t = blockIdx.x * 256 + threadIdx.x;
  if (t >= n8) return;
  f32x4 a = ((const f32x4*)src)[2 * t];
  f32x4 b = ((const f32x4*)src)[2 * t + 1];
  u16x8 o;
  o[0] = f2bf(a[0]); o[1] = f2bf(a[1]); o[2] = f2bf(a[2]); o[3] = f2bf(a[3]);
  o[4] = f2bf(b[0]); o[5] = f2bf(b[1]); o[6] = f2bf(b[2]); o[7] = f2bf(b[3]);
  ((u16x8*)dst)[t] = o;
}

// q:[O][G][128] int32 (flat == row-major [O][I]), s/z:[O][G] -> w bf16 [O][I]
// blockIdx.z selects tensor {0: w1, 1: w2}; both are 16.78M elements here.
__global__ __launch_bounds__(256) void dequant_w2x(const int* __restrict__ qa,
                                                   const float* __restrict__ sa,
                                                   const float* __restrict__ za,
                                                   u16* __restrict__ wa,
                                                   const int* __restrict__ qb,
                                                   const float* __restrict__ sb,
                                                   const float* __restrict__ zb,
                                                   u16* __restrict__ wb, int n8) {
  int t = blockIdx.x * 256 + threadIdx.x;
  if (t >= n8) return;
  const int* q = blockIdx.z ? qb : qa;
  const float* s = blockIdx.z ? sb : sa;
  const float* z = blockIdx.z ? zb : za;
  u16* w = blockIdx.z ? wb : wa;
  int g = t >> 4;                 // 8 elems/thread, 128 elems/group -> 16 threads/group
  float sc = s[g];
  float zp = z[g];
  i32x4 a = ((const i32x4*)q)[2 * t];
  i32x4 b = ((const i32x4*)q)[2 * t + 1];
  u16x8 o;
  o[0] = f2bf(((float)a[0] - zp) * sc);
  o[1] = f2bf(((float)a[1] - zp) * sc);
  o[2] = f2bf(((float)a[2] - zp) * sc);
  o[3] = f2bf(((float)a[3] - zp) * sc);
  o[4] = f2bf(((float)b[0] - zp) * sc);
  o[5] = f2bf(((float)b[1] - zp) * sc);
  o[6] = f2bf(((float)b[2] - zp) * sc);
  o[7] = f2bf(((float)b[3] - zp) * sc);
  ((u16x8*)w)[t] = o;
}

__global__ __launch_bounds__(256) void bias_init(float* __restrict__ out,
                                                 const float* __restrict__ b,
                                                 int N, int n4) {
  int t = blockIdx.x * 256 + threadIdx.x;
  if (t >= n4) return;
  int idx = t * 4;
  int n = idx & (N - 1);          // N is a power of two (2048)
  *(f32x4*)(out + idx) = *(const f32x4*)(b + n);
}

// ---------------- NT GEMM: C[M,N] = A[M,K] * B[N,K]^T (+bias, relu) ----------------
// 64x64 tile, 4 waves in 2x2, each wave 32x32 via 2x2 MFMA 16x16x32 bf16, BK=32.
// OCCUPANCY EXPERIMENT (r0/r1/r6/r7 post-mortem): only blocks/CU ever moved GEMM
// time (2/CU=48us, 1/CU=80us); no pipe is >25% busy. 64^2 tiles -> 1024 blocks
// = 4 blocks/CU, 16 waves/CU, LDS 16KB/block.
// Staging/swizzle/sync are the r1/r7-verified forms verbatim:
//   - per wave: 1 GLD16 A + 1 GLD16 B per stage (wave stages its own 16 rows)
//   - swizzle LDS(row,c)=global(row, c^((row>>1)&3)), read cs=(quad^((l15>>1)&3))<<3
//     (0 bank conflicts measured r1/r3/r6/r7)
//   - 2-deep counted-vmcnt: steady vmcnt(2), tails vmcnt(2)/vmcnt(0); wait-then-barrier.
template <bool RELU, bool OUT_BF16, bool ATOMIC>
__global__ __launch_bounds__(256) void gemm64(const u16* __restrict__ A,
                                              const u16* __restrict__ Bm,
                                              const float* __restrict__ bias,
                                              void* __restrict__ Cout,
                                              int N, int K, int kChunk) {
  __shared__ u16 As[2][64 * 32];   // 2 x 4KB
  __shared__ u16 Bs[2][64 * 32];   // 2 x 4KB  (total 16KB)
  const int tid = threadIdx.x;
  const int wave = tid >> 6;
  const int lane = tid & 63;
  const int m0 = blockIdx.y << 6;
  const int n0 = blockIdx.x << 6;
  const int kStart = blockIdx.z * kChunk;
  const int srow = lane >> 2;         // staging: 16 rows x 4 lanes*16B = 1KB per GLD16
  const int scol = (((lane & 3) ^ ((lane >> 3) & 3)) << 3);   // pre-swizzled src chunk
  const int wm = (wave >> 1) << 5;    // 0 or 32
  const int wn = (wave & 1) << 5;     // 0 or 32
  const int quad = lane >> 4;
  const int l15 = lane & 15;
  const int cs = ((quad ^ ((l15 >> 1) & 3)) << 3);            // swizzled read offset

  const u16* Ab = A + (size_t)(m0 + 16 * wave + srow) * K + kStart + scol;
  const u16* Bb = Bm + (size_t)(n0 + 16 * wave + srow) * K + kStart + scol;
  const int ldsS = (16 * wave) * 32;  // u16 offset of this wave's 16-row staging region
  const int nT = kChunk >> 5;         // 64 steps for both GEMMs here (>= 2)

  f32x4 acc[2][2];
#pragma unroll
  for (int i = 0; i < 2; i++)
#pragma unroll
    for (int j = 0; j < 2; j++) acc[i][j] = (f32x4){0.f, 0.f, 0.f, 0.f};

  // stage K-step t_ into buffer bi_ : exactly 2 GLD16 per wave (vmcnt counts on this)
#define STAGE(bi_, t_)                                    \
  do {                                                    \
    const int ko_ = (t_) << 5;                            \
    GLD16(Ab + ko_, &As[bi_][ldsS]);                      \
    GLD16(Bb + ko_, &Bs[bi_][ldsS]);                      \
  } while (0)

  bf16x8 af[2], bf[2];
#define LOADFRAGS(bi_)                                                        \
  do {                                                                        \
    _Pragma("unroll") for (int i = 0; i < 2; i++)                             \
        af[i] = *(const bf16x8*)&As[bi_][(wm + i * 16 + l15) * 32 + cs];      \
    _Pragma("unroll") for (int j = 0; j < 2; j++)                             \
        bf[j] = *(const bf16x8*)&Bs[bi_][(wn + j * 16 + l15) * 32 + cs];      \
  } while (0)

#define DOMFMA()                                                              \
  do {                                                                        \
    _Pragma("unroll") for (int i = 0; i < 2; i++)                             \
        _Pragma("unroll") for (int j = 0; j < 2; j++)                         \
            acc[i][j] = __builtin_amdgcn_mfma_f32_16x16x32_bf16(              \
                af[i], bf[j], acc[i][j], 0, 0, 0);                            \
  } while (0)

  // prologue: fill the 2-deep pipe (4 loads in flight per wave)
  STAGE(0, 0);
  STAGE(1, 1);

  // main loop: t in [0, nT-2)
  for (int t = 0; t < nT - 2; ++t) {
    // outstanding = stages {t, t+1} = 4; retire the oldest 2 (stage t)
    asm volatile("s_waitcnt vmcnt(2)" ::: "memory");
    __builtin_amdgcn_s_barrier();              // all waves' stage(t) visible in LDS
    LOADFRAGS(t & 1);                          // 4 ds_read_b128
    asm volatile("s_waitcnt lgkmcnt(0)" ::: "memory");   // frags landed in regs
    __builtin_amdgcn_sched_barrier(0);         // rule #18
    __builtin_amdgcn_s_barrier();              // all waves done reading buf
    STAGE(t & 1, t + 2);                       // overwrite with tile t+2
    DOMFMA();                                  // overlaps stage issue
  }
  // t = nT-2: outstanding {nT-2, nT-1} = 4; retire oldest 2; no further staging
  asm volatile("s_waitcnt vmcnt(2)" ::: "memory");
  __builtin_amdgcn_s_barrier();
  LOADFRAGS((nT - 2) & 1);
  asm volatile("s_waitcnt lgkmcnt(0)" ::: "memory");
  __builtin_amdgcn_sched_barrier(0);
  DOMFMA();
  // t = nT-1: drain
  asm volatile("s_waitcnt vmcnt(0)" ::: "memory");
  __builtin_amdgcn_s_barrier();
  LOADFRAGS((nT - 1) & 1);
  asm volatile("s_waitcnt lgkmcnt(0)" ::: "memory");
  __builtin_amdgcn_sched_barrier(0);
  DOMFMA();

#undef STAGE
#undef LOADFRAGS
#undef DOMFMA

  // epilogue: C/D layout col=lane&15, row=quad*4+reg (verified m89/m91)
#pragma unroll
  for (int i = 0; i < 2; i++) {
#pragma unroll
    for (int j = 0; j < 2; j++) {
      const int col = n0 + wn + j * 16 + l15;
      float bv = 0.f;
      if (!ATOMIC) bv = bias[col];
#pragma unroll
      for (int r = 0; r < 4; r++) {
        const int row = m0 + wm + i * 16 + quad * 4 + r;
        float v = acc[i][j][r];
        if (ATOMIC) {
          atomicAdd((float*)Cout + (size_t)row * N + col, v);
        } else {
          v += bv;
          if (RELU) v = v > 0.f ? v : 0.f;
          if (OUT_BF16)
            ((u16*)Cout)[(size_t)row * N + col] = f2bf(v);
          else
            ((float*)Cout)[(size_t)row * N + col] = v;
        }
      }
    }
  }
}

// ---------------- launch ----------------

extern "C" void kernel_launch(void* const* d_in, const int* in_sizes, int n_in,
                              void* d_out, int out_size, void* d_ws, size_t ws_size,
                              hipStream_t stream) {
  const float* x  = (const float*)d_in[0];
  const int*   q1 = (const int*)d_in[1];
  const float* s1 = (const float*)d_in[2];
  const float* z1 = (const float*)d_in[3];
  const float* b1 = (const float*)d_in[4];
  const int*   q2 = (const int*)d_in[5];
  const float* s2 = (const float*)d_in[6];
  const float* z2 = (const float*)d_in[7];
  const float* b2 = (const float*)d_in[8];
  float* out = (float*)d_out;

  const int B = 512, D_IN = 2048, D_H = 8192, D_OUT = 2048;

  char* ws = (char*)d_ws;
  u16* xb  = (u16*)(ws);                                   //  2 MB: x bf16 [512][2048]
  u16* w1b = (u16*)(ws + (size_t)2 * 1024 * 1024);         // 32 MB: w1 bf16 [8192][2048]
  u16* hb  = (u16*)(ws + (size_t)34 * 1024 * 1024);        //  8 MB: h bf16 [512][8192]
  u16* w2b = (u16*)(ws + (size_t)42 * 1024 * 1024);        // 32 MB: w2 bf16 [2048][8192]

  // 1. x -> bf16
  cvt_f32_bf16<<<(B * D_IN / 8 + 255) / 256, 256, 0, stream>>>(x, xb, B * D_IN / 8);
  // 2. dequant both weights -> bf16 (one launch; both tensors are 16.78M elems)
  {
    const int n8 = D_H * D_IN / 8;            // == D_OUT * D_H / 8
    dim3 gd((n8 + 255) / 256, 1, 2);
    dequant_w2x<<<gd, 256, 0, stream>>>(q1, s1, z1, w1b, q2, s2, z2, w2b, n8);
  }
  // 3. h = relu(x @ w1^T + b1), bf16 out, fused epilogue, no split.
  //    64x64 tiles -> grid (128, 8) = 1024 blocks = 4/CU. nT = 64.
  {
    dim3 g1(D_H / 64, B / 64, 1);
    gemm64<true, true, false><<<g1, 256, 0, stream>>>(xb, w1b, b1, hb,
                                                      D_H, D_IN, D_IN);
  }
  // 4. out = b2 broadcast, then split-K=4 atomic: out += h @ w2^T.
  //    64x64 tiles -> grid (32, 8, 4) = 1024 blocks = 4/CU. nT = 64. WRITE 16MB.
  bias_init<<<(B * D_OUT / 4 + 255) / 256, 256, 0, stream>>>(out, b2, D_OUT, B * D_OUT / 4);
  {
    dim3 g2(D_OUT / 64, B / 64, 4);
    gemm64<false, false, true><<<g2, 256, 0, stream>>>(hb, w2b, nullptr, out,
                                                       D_OUT, D_H, D_H / 4);
  }
}

// Round 10
// 249.203 us; speedup vs baseline: 1.0959x; 1.0003x over previous
//
#include <hip/hip_runtime.h>
#include <stdint.h>

typedef unsigned short u16;
typedef __attribute__((ext_vector_type(8))) short bf16x8;   // 8 bf16 = 4 VGPRs (MFMA A/B frag)
typedef __attribute__((ext_vector_type(8))) unsigned short u16x8;
typedef __attribute__((ext_vector_type(4))) float f32x4;
typedef __attribute__((ext_vector_type(4))) int i32x4;

__device__ __forceinline__ u16 f2bf(float f) {
  uint32_t u = __builtin_bit_cast(uint32_t, f);
  u += 0x7fffu + ((u >> 16) & 1u);   // RNE
  return (u16)(u >> 16);
}

// async global->LDS, 16B per lane; LDS dest must be wave-uniform base (+lane*16 implicit)
#define GLD16(g, l)                                                         \
  __builtin_amdgcn_global_load_lds(                                         \
      (const __attribute__((address_space(1))) void*)(g),                   \
      (__attribute__((address_space(3))) void*)(l), 16, 0, 0)

// ---------------- elementwise prep kernels ----------------

__global__ __launch_bounds__(256) void cvt_f32_bf16(const float* __restrict__ src,
                                                    u16* __restrict__ dst, int n8) {
  int t = blockIdx.x * 256 + threadIdx.x;
  if (t >= n8) return;
  f32x4 a = ((const f32x4*)src)[2 * t];
  f32x4 b = ((const f32x4*)src)[2 * t + 1];
  u16x8 o;
  o[0] = f2bf(a[0]); o[1] = f2bf(a[1]); o[2] = f2bf(a[2]); o[3] = f2bf(a[3]);
  o[4] = f2bf(b[0]); o[5] = f2bf(b[1]); o[6] = f2bf(b[2]); o[7] = f2bf(b[3]);
  ((u16x8*)dst)[t] = o;
}

// q:[O][G][128] int32 (flat == row-major [O][I]), s/z:[O][G] -> w bf16 [O][I]
// v2 (r9 post-mortem): dequant was 3.6 TB/s effective (40-55% of achievable),
// VALUBusy 9% -> not compute-limited; one-shot 8-elem threads lacked MLP.
// Now grid-stride, 16 elems / thread-iter (64B in, 32B out; 4 indep loads +
// 2 indep stores in flight), 4 iters/thread, 2048 blocks total (8/CU).
// Math is bit-identical to the verified kernel: ((float)q - zp) * sc, RNE bf16.
// blockIdx.z selects tensor {0: w1, 1: w2}; both are 16.78M elements here.
__global__ __launch_bounds__(256) void dequant_w2x(const int* __restrict__ qa,
                                                   const float* __restrict__ sa,
                                                   const float* __restrict__ za,
                                                   u16* __restrict__ wa,
                                                   const int* __restrict__ qb,
                                                   const float* __restrict__ sb,
                                                   const float* __restrict__ zb,
                                                   u16* __restrict__ wb, int n16) {
  const int* q = blockIdx.z ? qb : qa;
  const float* s = blockIdx.z ? sb : sa;
  const float* z = blockIdx.z ? zb : za;
  u16* w = blockIdx.z ? wb : wa;
  const int stride = gridDim.x * 256;
  for (int t = blockIdx.x * 256 + threadIdx.x; t < n16; t += stride) {
    const int g = t >> 3;               // 16 elems/iter, 128 elems/group -> 8 iters/group
    const float sc = s[g];
    const float zp = z[g];
    i32x4 a = ((const i32x4*)q)[4 * t];
    i32x4 b = ((const i32x4*)q)[4 * t + 1];
    i32x4 c = ((const i32x4*)q)[4 * t + 2];
    i32x4 d = ((const i32x4*)q)[4 * t + 3];
    u16x8 o0, o1;
#pragma unroll
    for (int e = 0; e < 4; e++) {
      o0[e]     = f2bf(((float)a[e] - zp) * sc);
      o0[e + 4] = f2bf(((float)b[e] - zp) * sc);
      o1[e]     = f2bf(((float)c[e] - zp) * sc);
      o1[e + 4] = f2bf(((float)d[e] - zp) * sc);
    }
    ((u16x8*)w)[2 * t] = o0;
    ((u16x8*)w)[2 * t + 1] = o1;
  }
}

__global__ __launch_bounds__(256) void bias_init(float* __restrict__ out,
                                                 const float* __restrict__ b,
                                                 int N, int n4) {
  int t = blockIdx.x * 256 + threadIdx.x;
  if (t >= n4) return;
  int idx = t * 4;
  int n = idx & (N - 1);          // N is a power of two (2048)
  *(f32x4*)(out + idx) = *(const f32x4*)(b + n);
}

// ---------------- NT GEMM: C[M,N] = A[M,K] * B[N,K]^T (+bias, relu) ----------------
// r7-verified template, unchanged. BM=128, BN=32*NJ. 4 waves 2x2, each wave
// 64 x 16*NJ via 4xNJ MFMA 16x16x32 bf16, BK=32.
// r1-verified staging/swizzle: GLD16 covers 16 rows; pre-swizzled global source
// chunk scol = ((l&3)^((l>>3)&3))<<3; read cs = (quad^((l15>>1)&3))<<3
// (0 bank conflicts measured r1/r3/r6/r7/r9).
// r6-verified 2-deep counted-vmcnt sync: steady vmcnt(VM), tails vmcnt(VM)/vmcnt(0);
// VM = GLD16s per stage per wave = 2 (A) + NJ/2 (B).
// Config (composition of best-measured): gemm1 = NJ=2, 512 blocks, fused epilogue
// (r7: ~43-46us); gemm2 = NJ=4, split-K=8 (r1/r3: 48.16us; r7's split-16 was the
// regression -> WRITE back to 32MB).
template <int NJ, bool RELU, bool OUT_BF16, bool ATOMIC>
__global__ __launch_bounds__(256) void gemm_bt(const u16* __restrict__ A,
                                               const u16* __restrict__ Bm,
                                               const float* __restrict__ bias,
                                               void* __restrict__ Cout,
                                               int N, int K, int kChunk) {
  __shared__ u16 As[2][128 * 32];        // 2 x 8KB
  __shared__ u16 Bs[2][32 * NJ * 32];    // 2 x 2KB*NJ  (NJ=4: 32KB total; NJ=2: 24KB)
  const int tid = threadIdx.x;
  const int wave = tid >> 6;
  const int lane = tid & 63;
  const int m0 = blockIdx.y << 7;
  const int n0 = blockIdx.x * (32 * NJ);
  const int kStart = blockIdx.z * kChunk;
  const int srow = lane >> 2;            // 16 rows x 4 lanes*16B = 1KB per GLD16
  const int scol = (((lane & 3) ^ ((lane >> 3) & 3)) << 3);   // pre-swizzled src chunk
  const int wm = (wave >> 1) << 6;
  const int wn = (wave & 1) * (16 * NJ);
  const int quad = lane >> 4;
  const int l15 = lane & 15;
  const int cs = ((quad ^ ((l15 >> 1) & 3)) << 3);            // swizzled read offset

  const u16* Ab = A + (size_t)(m0 + 32 * wave + srow) * K + kStart + scol;
  const u16* Bb = Bm + (size_t)(n0 + (8 * NJ) * wave + srow) * K + kStart + scol;
  const int ldsA = (32 * wave) * 32;     // wave's 32-row A staging region (u16 offset)
  const int ldsB = ((8 * NJ) * wave) * 32;   // wave's 8*NJ-row B staging region
  const size_t rowskip = (size_t)16 * K;
  const int nT = kChunk >> 5;            // #BK=32 steps (>= 2)
  constexpr int VM = 2 + NJ / 2;         // GLD16s per stage per wave

  f32x4 acc[4][NJ];
#pragma unroll
  for (int i = 0; i < 4; i++)
#pragma unroll
    for (int j = 0; j < NJ; j++) acc[i][j] = (f32x4){0.f, 0.f, 0.f, 0.f};

  // stage K-step t_ into buffer bi_ : exactly VM GLD16 per wave (vmcnt counts on this)
#define STAGE(bi_, t_)                                        \
  do {                                                        \
    const int ko_ = (t_) << 5;                                \
    GLD16(Ab + ko_, &As[bi_][ldsA]);                          \
    GLD16(Ab + ko_ + rowskip, &As[bi_][ldsA + 512]);          \
    GLD16(Bb + ko_, &Bs[bi_][ldsB]);                          \
    if (NJ == 4) GLD16(Bb + ko_ + rowskip, &Bs[bi_][ldsB + 512]); \
  } while (0)

  bf16x8 af[4], bf[NJ];
#define LOADFRAGS(bi_)                                                        \
  do {                                                                        \
    _Pragma("unroll") for (int i = 0; i < 4; i++)                             \
        af[i] = *(const bf16x8*)&As[bi_][(wm + i * 16 + l15) * 32 + cs];      \
    _Pragma("unroll") for (int j = 0; j < NJ; j++)                            \
        bf[j] = *(const bf16x8*)&Bs[bi_][(wn + j * 16 + l15) * 32 + cs];      \
  } while (0)

#define DOMFMA()                                                              \
  do {                                                                        \
    _Pragma("unroll") for (int i = 0; i < 4; i++)                             \
        _Pragma("unroll") for (int j = 0; j < NJ; j++)                        \
            acc[i][j] = __builtin_amdgcn_mfma_f32_16x16x32_bf16(              \
                af[i], bf[j], acc[i][j], 0, 0, 0);                            \
  } while (0)

  // prologue: fill the 2-deep pipe (2*VM loads in flight per wave)
  STAGE(0, 0);
  STAGE(1, 1);

  // main loop: t in [0, nT-2)
  for (int t = 0; t < nT - 2; ++t) {
    // outstanding = stages {t, t+1} = 2*VM; retire the oldest VM (stage t)
    asm volatile("s_waitcnt vmcnt(%0)" ::"i"(VM) : "memory");
    __builtin_amdgcn_s_barrier();              // all waves' stage(t) visible in LDS
    LOADFRAGS(t & 1);
    asm volatile("s_waitcnt lgkmcnt(0)" ::: "memory");   // frags landed in regs
    __builtin_amdgcn_sched_barrier(0);         // rule #18
    __builtin_amdgcn_s_barrier();              // all waves done reading buf
    STAGE(t & 1, t + 2);                       // overwrite with tile t+2
    DOMFMA();                                  // overlaps stage issue
  }
  // t = nT-2: outstanding {nT-2, nT-1} = 2*VM; retire oldest VM; no further staging
  asm volatile("s_waitcnt vmcnt(%0)" ::"i"(VM) : "memory");
  __builtin_amdgcn_s_barrier();
  LOADFRAGS((nT - 2) & 1);
  asm volatile("s_waitcnt lgkmcnt(0)" ::: "memory");
  __builtin_amdgcn_sched_barrier(0);
  DOMFMA();
  // t = nT-1: drain
  asm volatile("s_waitcnt vmcnt(0)" ::: "memory");
  __builtin_amdgcn_s_barrier();
  LOADFRAGS((nT - 1) & 1);
  asm volatile("s_waitcnt lgkmcnt(0)" ::: "memory");
  __builtin_amdgcn_sched_barrier(0);
  DOMFMA();

#undef STAGE
#undef LOADFRAGS
#undef DOMFMA

  // epilogue: C/D layout col=lane&15, row=quad*4+reg (verified m89/m91)
#pragma unroll
  for (int i = 0; i < 4; i++) {
#pragma unroll
    for (int j = 0; j < NJ; j++) {
      const int col = n0 + wn + j * 16 + l15;
      float bv = 0.f;
      if (!ATOMIC) bv = bias[col];
#pragma unroll
      for (int r = 0; r < 4; r++) {
        const int row = m0 + wm + i * 16 + quad * 4 + r;
        float v = acc[i][j][r];
        if (ATOMIC) {
          atomicAdd((float*)Cout + (size_t)row * N + col, v);
        } else {
          v += bv;
          if (RELU) v = v > 0.f ? v : 0.f;
          if (OUT_BF16)
            ((u16*)Cout)[(size_t)row * N + col] = f2bf(v);
          else
            ((float*)Cout)[(size_t)row * N + col] = v;
        }
      }
    }
  }
}

// ---------------- launch ----------------

extern "C" void kernel_launch(void* const* d_in, const int* in_sizes, int n_in,
                              void* d_out, int out_size, void* d_ws, size_t ws_size,
                              hipStream_t stream) {
  const float* x  = (const float*)d_in[0];
  const int*   q1 = (const int*)d_in[1];
  const float* s1 = (const float*)d_in[2];
  const float* z1 = (const float*)d_in[3];
  const float* b1 = (const float*)d_in[4];
  const int*   q2 = (const int*)d_in[5];
  const float* s2 = (const float*)d_in[6];
  const float* z2 = (const float*)d_in[7];
  const float* b2 = (const float*)d_in[8];
  float* out = (float*)d_out;

  const int B = 512, D_IN = 2048, D_H = 8192, D_OUT = 2048;

  char* ws = (char*)d_ws;
  u16* xb  = (u16*)(ws);                                   //  2 MB: x bf16 [512][2048]
  u16* w1b = (u16*)(ws + (size_t)2 * 1024 * 1024);         // 32 MB: w1 bf16 [8192][2048]
  u16* hb  = (u16*)(ws + (size_t)34 * 1024 * 1024);        //  8 MB: h bf16 [512][8192]
  u16* w2b = (u16*)(ws + (size_t)42 * 1024 * 1024);        // 32 MB: w2 bf16 [2048][8192]

  // 1. x -> bf16
  cvt_f32_bf16<<<(B * D_IN / 8 + 255) / 256, 256, 0, stream>>>(x, xb, B * D_IN / 8);
  // 2. dequant both weights -> bf16 (grid-stride v2: 2048 blocks, 4 iters/thread)
  {
    const int n16 = D_H * D_IN / 16;          // == D_OUT * D_H / 16 = 1048576
    dim3 gd(1024, 1, 2);
    dequant_w2x<<<gd, 256, 0, stream>>>(q1, s1, z1, w1b, q2, s2, z2, w2b, n16);
  }
  // 3. h = relu(x @ w1^T + b1), bf16 out, fused epilogue.
  //    BN=64 tiles -> grid (128,4) = 512 blocks (2+/CU). nT = 64.  [r7 config]
  {
    dim3 g1(D_H / 64, B / 128, 1);
    gemm_bt<2, true, true, false><<<g1, 256, 0, stream>>>(xb, w1b, b1, hb,
                                                          D_H, D_IN, D_IN);
  }
  // 4. out = b2 broadcast, then split-K=8 atomic: out += h @ w2^T.
  //    128x128 tiles -> grid (16,4,8) = 512 blocks, WRITE 32MB. nT = 32. [r1/r3 config]
  bias_init<<<(B * D_OUT / 4 + 255) / 256, 256, 0, stream>>>(out, b2, D_OUT, B * D_OUT / 4);
  {
    dim3 g2(D_OUT / 128, B / 128, 8);
    gemm_bt<4, false, false, true><<<g2, 256, 0, stream>>>(hb, w2b, nullptr, out,
                                                           D_OUT, D_H, D_H / 8);
  }
}